// Round 1
// 794.909 us; speedup vs baseline: 1.1106x; 1.1106x over previous
//
#include <hip/hip_runtime.h>

// Problem constants
#define Bn   32
#define Cc   512
#define CIc  256
#define Nsp  3136      // 56*56
#define Npad 3200      // spatial padded to multiple of 128 (tile coverage)
#define EPSbn 1e-5f

typedef __attribute__((ext_vector_type(8))) short v8s;   // 8 x bf16 (4 VGPRs)
typedef __attribute__((ext_vector_type(4))) float v4f;   // MFMA accumulator

__device__ __forceinline__ unsigned short f2bf(float f) {
    unsigned int u = __builtin_bit_cast(unsigned int, f);
    u += 0x7fffu + ((u >> 16) & 1u);          // RNE
    return (unsigned short)(u >> 16);
}

__device__ __forceinline__ float bf2f(unsigned short u) {
    unsigned int x = ((unsigned int)u) << 16;
    return __builtin_bit_cast(float, x);
}

// async global->LDS, 16B per lane; LDS dest = wave-uniform base + lane*16
__device__ __forceinline__ void async16(const unsigned short* g, unsigned short* l) {
    __builtin_amdgcn_global_load_lds(
        (const __attribute__((address_space(1))) unsigned int*)g,
        (__attribute__((address_space(3))) unsigned int*)l, 16, 0, 0);
}

// Canonical bf16 MFMA GEMM:  O[gn][gm] = sum_k A[gm][k] * B[gn][k]
// A: [M][lda] bf16 (k-contig), B: [N][ldb] bf16 (k-contig).
// Block tile 128x128 (M x N), BK=32, 4 waves in 2x2, 4x4 16x16x32 MFMAs/wave.
// EPI 0: bf16 store O[gn][gm] (+ optional biasN[bN_bs*b + gn], * scale)
// EPI 2: z = acc + biasN[gc] + x[b][gc][gsp]; store z bf16 [c][n] (gsp<Nsp);
//        per-channel sum/sumsq atomics into stats
template <int EPI>
__global__ __launch_bounds__(256)
void mfma_gemm(const unsigned short* __restrict__ A, int lda, long a_bs,
               const unsigned short* __restrict__ B, int ldb, long b_bs,
               void* __restrict__ Out, int ldo, long o_bs,
               int K, float scale,
               const float* __restrict__ biasN, long bN_bs,
               const float* __restrict__ xres,
               float* __restrict__ stats)
{
    __shared__ __align__(16) unsigned short As[128 * 32];  // [m][k] 8KB
    __shared__ __align__(16) unsigned short Bs[128 * 32];  // [n][k] 8KB

    const int tid  = threadIdx.x;
    const int w    = tid >> 6;
    const int lane = tid & 63;
    const int b    = blockIdx.z;
    const int m0   = blockIdx.x * 128;
    const int n0   = blockIdx.y * 128;

    const unsigned short* Ab = A + (long)b * a_bs;
    const unsigned short* Bb = B + (long)b * b_bs;

    // staging map: chunk c = 2w+q covers LDS elems [c*512,(c+1)*512), lane elem = c*512+lane*8
    const int ldrow = 32 * w + (lane >> 2);
    const int ldk   = (lane & 3) * 8;
    unsigned short* lA0 = &As[(2 * w + 0) * 512];
    unsigned short* lA1 = &As[(2 * w + 1) * 512];
    unsigned short* lB0 = &Bs[(2 * w + 0) * 512];
    unsigned short* lB1 = &Bs[(2 * w + 1) * 512];
    const size_t aoff0 = (size_t)(m0 + ldrow) * lda + ldk;
    const size_t aoff1 = aoff0 + (size_t)16 * lda;
    const size_t boff0 = (size_t)(n0 + ldrow) * ldb + ldk;
    const size_t boff1 = boff0 + (size_t)16 * ldb;

    const int wm = (w & 1) * 64;       // wave tile M offset
    const int wn = (w >> 1) * 64;      // wave tile N offset
    const int fr = lane & 15;
    const int fk = (lane >> 4) * 8;

    v4f acc[4][4] = {};

    for (int k0 = 0; k0 < K; k0 += 32) {
        __syncthreads();                        // previous tile's ds_reads done
        async16(Ab + aoff0 + k0, lA0);
        async16(Ab + aoff1 + k0, lA1);
        async16(Bb + boff0 + k0, lB0);
        async16(Bb + boff1 + k0, lB1);
        __syncthreads();                        // drains vmcnt -> LDS valid

        v8s af[4], bf[4];
#pragma unroll
        for (int i = 0; i < 4; ++i)
            af[i] = *(const v8s*)&As[(wm + i * 16 + fr) * 32 + fk];
#pragma unroll
        for (int j = 0; j < 4; ++j)
            bf[j] = *(const v8s*)&Bs[(wn + j * 16 + fr) * 32 + fk];
#pragma unroll
        for (int i = 0; i < 4; ++i)
#pragma unroll
            for (int j = 0; j < 4; ++j)
                acc[i][j] = __builtin_amdgcn_mfma_f32_16x16x32_bf16(af[i], bf[j], acc[i][j], 0, 0, 0);
    }

    // C/D layout: col(n-role)=lane&15, row(m-role)=quad*4+reg -> 4 consecutive m per lane
    const int em = wm + ((lane >> 4) << 2);
    const int en = wn + fr;

    if constexpr (EPI == 0) {
        unsigned short* O = (unsigned short*)Out;
#pragma unroll
        for (int j = 0; j < 4; ++j) {
            const int gn = n0 + en + j * 16;
            const float bN = biasN ? biasN[bN_bs * b + gn] : 0.0f;
            unsigned short* orow = O + (long)b * o_bs + (size_t)gn * ldo + m0 + em;
#pragma unroll
            for (int i = 0; i < 4; ++i) {
                ushort4 o4;
                o4.x = f2bf(acc[i][j].x * scale + bN);
                o4.y = f2bf(acc[i][j].y * scale + bN);
                o4.z = f2bf(acc[i][j].z * scale + bN);
                o4.w = f2bf(acc[i][j].w * scale + bN);
                *(ushort4*)&orow[i * 16] = o4;
            }
        }
    } else {  // EPI == 2: z = acc + W_b + x residual; store bf16 z; batch-norm stats
        unsigned short* O = (unsigned short*)Out;
        float sj[4] = {0.f, 0.f, 0.f, 0.f}, qj[4] = {0.f, 0.f, 0.f, 0.f};
#pragma unroll
        for (int j = 0; j < 4; ++j) {
            const int gc = n0 + en + j * 16;
            const float wb = biasN[gc];
            const float* xrow = xres + (size_t)b * Cc * Nsp + (size_t)gc * Nsp;
            unsigned short* zrow = O + (long)b * o_bs + (size_t)gc * ldo;
#pragma unroll
            for (int i = 0; i < 4; ++i) {
                const int gsp = m0 + em + i * 16;
                if (gsp < Nsp) {
                    const float4 xr = *(const float4*)&xrow[gsp];
                    const float z0 = acc[i][j].x + wb + xr.x;
                    const float z1 = acc[i][j].y + wb + xr.y;
                    const float z2 = acc[i][j].z + wb + xr.z;
                    const float z3 = acc[i][j].w + wb + xr.w;
                    sj[j] += z0 + z1 + z2 + z3;
                    qj[j] += z0 * z0 + z1 * z1 + z2 * z2 + z3 * z3;
                    ushort4 o4;
                    o4.x = f2bf(z0); o4.y = f2bf(z1); o4.z = f2bf(z2); o4.w = f2bf(z3);
                    *(ushort4*)&zrow[gsp] = o4;
                }
            }
        }
        __syncthreads();                       // done reading As -> reuse as scratch
        float* red = (float*)As;               // [128][8] sums + [128][8] sumsq (8KB exactly)
        const int cid = (lane >> 4) + ((w & 1) << 2);
#pragma unroll
        for (int j = 0; j < 4; ++j) {
            const int cc = wn + fr + j * 16;
            red[cc * 8 + cid] = sj[j];
            red[1024 + cc * 8 + cid] = qj[j];
        }
        __syncthreads();
        if (tid < 128) {
            float s = 0.f, q = 0.f;
#pragma unroll
            for (int t = 0; t < 8; ++t) { s += red[tid * 8 + t]; q += red[1024 + tid * 8 + t]; }
            atomicAdd(&stats[n0 + tid], s);
            atomicAdd(&stats[Cc + n0 + tid], q);
        }
    }
}

// x fp32 [b][c][n] -> xT bf16 [b][n][c] (n rows = 3136, unpadded; OOB reads tolerated downstream)
__global__ __launch_bounds__(256)
void cast_transpose(const float* __restrict__ x, unsigned short* __restrict__ xT)
{
    __shared__ float tile[64][65];
    const int b  = blockIdx.z;
    const int n0 = blockIdx.x * 64;
    const int c0 = blockIdx.y * 64;
    const float* xb = x + (size_t)b * Cc * Nsp;
    const int t = threadIdx.x;
    const int tr  = t >> 4;            // 0..15
    const int tc4 = (t & 15) * 4;
#pragma unroll
    for (int i = 0; i < 4; ++i) {
        const int c = tr + i * 16;
        const float4 v = *(const float4*)&xb[(size_t)(c0 + c) * Nsp + n0 + tc4];
        tile[tc4 + 0][c] = v.x;
        tile[tc4 + 1][c] = v.y;
        tile[tc4 + 2][c] = v.z;
        tile[tc4 + 3][c] = v.w;
    }
    __syncthreads();
    unsigned short* xo = xT + (size_t)b * Nsp * Cc;
#pragma unroll
    for (int i = 0; i < 4; ++i) {
        const int n = tr + i * 16;
        ushort4 o;
        o.x = f2bf(tile[n][tc4 + 0]);
        o.y = f2bf(tile[n][tc4 + 1]);
        o.z = f2bf(tile[n][tc4 + 2]);
        o.w = f2bf(tile[n][tc4 + 3]);
        *(ushort4*)&xo[(size_t)(n0 + n) * Cc + c0 + tc4] = o;
    }
}

__global__ void cast_w(const float* __restrict__ src, unsigned short* __restrict__ dst, int n)
{
    const int i = (blockIdx.x * 256 + threadIdx.x) * 4;
    if (i < n) {
        const float4 v = *(const float4*)&src[i];
        ushort4 o;
        o.x = f2bf(v.x); o.y = f2bf(v.y); o.z = f2bf(v.z); o.w = f2bf(v.w);
        *(ushort4*)&dst[i] = o;
    }
}

// g_w fp32 [256][512] -> gwT bf16 [512][256] (tiny; naive strided reads are fine)
__global__ void cast_wT(const float* __restrict__ src, unsigned short* __restrict__ dst)
{
    const int c = blockIdx.x;          // 512
    const int d = threadIdx.x;         // 256
    dst[(size_t)c * CIc + d] = f2bf(src[(size_t)d * Cc + c]);
}

// Fgb[b][c'] = sum_d F[b][c'][d] * g_b[d]   (exact g-bias: y += F*g_b; g_b==0 in harness)
__global__ void fgb_kernel(const unsigned short* __restrict__ F, const float* __restrict__ g_b,
                           float* __restrict__ Fgb)
{
    const int b = blockIdx.x, cp = threadIdx.x;
    const unsigned short* Fr = F + ((size_t)b * CIc + cp) * CIc;
    float acc = 0.f;
    for (int d = 0; d < CIc; ++d) acc += bf2f(Fr[d]) * g_b[d];
    Fgb[(size_t)b * CIc + cp] = acc;
}

__global__ void finalize_stats(const float* __restrict__ stats, float* __restrict__ mstd)
{
    const int c = threadIdx.x;  // 512
    const float inv = 1.0f / (float)((long)Bn * Nsp);
    const float mean = stats[c] * inv;
    const float var  = stats[Cc + c] * inv - mean * mean;
    mstd[c] = mean;
    mstd[Cc + c] = rsqrtf(var + EPSbn);
}

// out[b][c][n] = (z16[b][c][n] - mean[c]) * rstd[c] * gamma[c] + beta[c]
// z16 layout [b][c][3136] bf16, fully contiguous; out fp32 same index space.
__global__ __launch_bounds__(256)
void bnorm_apply(const unsigned short* __restrict__ z, const float* __restrict__ mstd,
                 const float* __restrict__ gamma, const float* __restrict__ beta,
                 float* __restrict__ out)
{
    const int NG = Bn * Cc * (Nsp / 8);            // 6,422,528 groups of 8
    const int g = blockIdx.x * 256 + threadIdx.x;
    if (g >= NG) return;
    const int c = (g / (Nsp / 8)) & (Cc - 1);
    const float a1 = mstd[Cc + c] * gamma[c];
    const float a0 = beta[c] - mstd[c] * a1;
    const v8s zv = *(const v8s*)(z + (size_t)g * 8);
    float* op = out + (size_t)g * 8;
    float4 o0, o1;
    o0.x = bf2f((unsigned short)zv[0]) * a1 + a0;
    o0.y = bf2f((unsigned short)zv[1]) * a1 + a0;
    o0.z = bf2f((unsigned short)zv[2]) * a1 + a0;
    o0.w = bf2f((unsigned short)zv[3]) * a1 + a0;
    o1.x = bf2f((unsigned short)zv[4]) * a1 + a0;
    o1.y = bf2f((unsigned short)zv[5]) * a1 + a0;
    o1.z = bf2f((unsigned short)zv[6]) * a1 + a0;
    o1.w = bf2f((unsigned short)zv[7]) * a1 + a0;
    *(float4*)op = o0;
    *(float4*)(op + 4) = o1;
}

extern "C" void kernel_launch(void* const* d_in, const int* in_sizes, int n_in,
                              void* d_out, int out_size, void* d_ws, size_t ws_size,
                              hipStream_t stream)
{
    const float* x     = (const float*)d_in[0];
    const float* g_w   = (const float*)d_in[1];
    const float* g_b   = (const float*)d_in[2];
    const float* th_w  = (const float*)d_in[3];
    const float* th_b  = (const float*)d_in[4];
    const float* ph_w  = (const float*)d_in[5];
    const float* ph_b  = (const float*)d_in[6];
    const float* W_w   = (const float*)d_in[7];
    const float* W_b   = (const float*)d_in[8];
    const float* gamma = (const float*)d_in[9];
    const float* beta  = (const float*)d_in[10];
    float* out = (float*)d_out;

    // Pipeline (FG-trick: y = F*(g_w x) = (F*g_w) x, so g is never materialized):
    //  1. xT = cast_transpose(x)                      [b][n][c] bf16
    //  2. thph: [theta;phi][c_cat 512][n] = xT * [th_w;ph_w]^T  (one GEMM, exact biases)
    //  3. F[c][d] = (1/N) sum_n theta[c][n] phi[d][n]
    //  4. FG[c'][e] = sum_d F[c'][d] g_w[d][e] ; Fgb[c'] = F*g_b
    //  5. Y[n][c'] = sum_e FG[c'][e] xT[n][e] + Fgb[c']   (overwrites T2)
    //  6. z1: z[c][n] = sum_c' Y[n][c'] W_w[c][c'] + W_b + x  -> store z bf16 (into xT
    //     region, dead by now) + per-channel stats
    //  7. bnorm_apply: out = (z - mean) * rstd * gamma + beta   (pure streaming)
    //
    // ws layout (bf16 elems):
    //  xT [32][3136][512]   51,380,224   (reused as z16 [32][512][3136], same size)
    //  T2 [32][512][3200]   52,428,800   (theta|phi; later Y [32][3200][256])
    //  F  [32][256][256]     2,097,152
    //  FG [32][256][512]     4,194,304
    //  w16: thph [512][512], gwT [512][256], Ww [512][256]
    //  fp32: thph_b[512], Fgb[32*256], stats[1024], mstd[1024]
    unsigned short* xT  = (unsigned short*)d_ws;
    unsigned short* T2  = xT + (size_t)Bn * Nsp * Cc;
    unsigned short* F   = T2 + (size_t)Bn * Cc * Npad;
    unsigned short* FG  = F + (size_t)Bn * CIc * CIc;
    unsigned short* thph16 = FG + (size_t)Bn * CIc * Cc;
    unsigned short* gwT16  = thph16 + Cc * Cc;
    unsigned short* Ww16   = gwT16 + Cc * CIc;
    float* thph_b = (float*)(Ww16 + Cc * CIc);
    float* Fgb    = thph_b + Cc;
    float* stats  = Fgb + Bn * CIc;
    float* mstd   = stats + 2 * Cc;

    unsigned short* Y   = T2;    // y NHWC, overwrites theta/phi after FG
    unsigned short* z16 = xT;    // z bf16 [c][n], overwrites xT after y GEMM

    hipMemsetAsync(stats, 0, 2 * Cc * sizeof(float), stream);
    hipMemcpyAsync(thph_b, th_b, CIc * sizeof(float), hipMemcpyDeviceToDevice, stream);
    hipMemcpyAsync(thph_b + CIc, ph_b, CIc * sizeof(float), hipMemcpyDeviceToDevice, stream);

    const dim3 blk(256);
    const long xT_bs = (long)Nsp * Cc;
    const long t2_bs = (long)Cc * Npad;    // theta|phi [c_cat][n stride 3200]
    const long y_bs  = (long)Npad * CIc;   // Y [n][c' stride 256]

    cast_transpose<<<dim3(49, 8, Bn), blk, 0, stream>>>(x, xT);
    cast_w<<<dim3(128), blk, 0, stream>>>(th_w, thph16, 131072);
    cast_w<<<dim3(128), blk, 0, stream>>>(ph_w, thph16 + 131072, 131072);
    cast_w<<<dim3(128), blk, 0, stream>>>(W_w, Ww16, 131072);
    cast_wT<<<dim3(Cc), dim3(CIc), 0, stream>>>(g_w, gwT16);

    // theta|phi: O[c_cat][n] = sum_c xT[n][c]*thph[c_cat][c]   M=n(3200), N=c_cat(512), K=512
    mfma_gemm<0><<<dim3(25, 4, Bn), blk, 0, stream>>>(
        xT, Cc, xT_bs, thph16, Cc, 0, T2, Npad, t2_bs, Cc, 1.0f,
        thph_b, 0, nullptr, nullptr);
    // Gram: F[c][d] = (1/N) sum_n phi[d][n]*theta[c][n]   M=d(256), N=c(256), K=3136
    mfma_gemm<0><<<dim3(2, 2, Bn), blk, 0, stream>>>(
        T2 + (size_t)CIc * Npad, Npad, t2_bs, T2, Npad, t2_bs,
        F, CIc, (long)CIc * CIc, Nsp, 1.0f / (float)Nsp,
        nullptr, 0, nullptr, nullptr);
    // FG[c'][e] = sum_d gwT[e][d]*F[c'][d]   M=e(512), N=c'(256), K=256
    mfma_gemm<0><<<dim3(4, 2, Bn), blk, 0, stream>>>(
        gwT16, CIc, 0, F, CIc, (long)CIc * CIc, FG, Cc, (long)CIc * Cc, CIc, 1.0f,
        nullptr, 0, nullptr, nullptr);
    fgb_kernel<<<dim3(Bn), dim3(CIc), 0, stream>>>(F, g_b, Fgb);
    // y: Y[n][c'] = sum_e FG[c'][e]*xT[n][e] + Fgb[b][c']   M=c'(256), N=n(3200), K=512
    mfma_gemm<0><<<dim3(2, 25, Bn), blk, 0, stream>>>(
        FG, Cc, (long)CIc * Cc, xT, Cc, xT_bs, Y, CIc, y_bs, Cc, 1.0f,
        Fgb, CIc, nullptr, nullptr);
    // z (stats + bf16 store): z[c][n] = sum_c' Y[n][c']*W_w[c][c'] + W_b + x
    // M=n(3200), N=c(512), K=256 ; Out = z16 [c][3136] (masked gsp<Nsp)
    mfma_gemm<2><<<dim3(25, 4, Bn), blk, 0, stream>>>(
        Y, CIc, y_bs, Ww16, CIc, 0, z16, Nsp, (long)Cc * Nsp, CIc, 1.0f,
        W_b, 0, x, stats);
    finalize_stats<<<dim3(1), dim3(Cc), 0, stream>>>(stats, mstd);
    bnorm_apply<<<dim3((Bn * Cc * (Nsp / 8) + 255) / 256), blk, 0, stream>>>(
        z16, mstd, gamma, beta, out);
}